// Round 1
// baseline (128.889 us; speedup 1.0000x reference)
//
#include <hip/hip_runtime.h>
#include <hip/hip_bf16.h>

// Problem constants (from reference): 32 graphs x 128 nodes, F=64, HID=128, OUT=64
#define F_IN 64
#define HID 128
#define OUTF 64
#define NN 128
#define NB 32
#define TOTAL 4096

typedef short bf16x8 __attribute__((ext_vector_type(8)));
typedef float f32x4 __attribute__((ext_vector_type(4)));

// ---------------------------------------------------------------------------
// Prep: feat -> bf16; W1[1:129] -> bf16 transposed [col][k]; W2 -> bf16 [col][k]
// ---------------------------------------------------------------------------
__global__ void prep_kernel(const float* __restrict__ feat,
                            const float* __restrict__ W1,
                            const float* __restrict__ W2,
                            __hip_bfloat16* __restrict__ hb,
                            __hip_bfloat16* __restrict__ w1t,
                            __hip_bfloat16* __restrict__ w2t) {
  int idx = blockIdx.x * 256 + threadIdx.x;
  if (idx < TOTAL * F_IN) hb[idx] = __float2bfloat16(feat[idx]);
  if (idx < HID * HID) {
    int c = idx >> 7, k = idx & 127;
    w1t[c * HID + k] = __float2bfloat16(W1[(1 + k) * HID + c]);  // skip d2 row
    w2t[c * HID + k] = __float2bfloat16(W2[k * HID + c]);
  }
}

// ---------------------------------------------------------------------------
// Main: one block per (graph b, node i). Rows = pairs (i, j), j=0..127.
// layer1: acc = b1 + d2*W1row0 (f32 exact) + [hj|hi] @ W1[1:]  (bf16 MFMA)
// layer2: acc = b2 + silu(z1) @ W2                             (bf16 MFMA)
// then column-sum of silu(z2) -> part[bid][128]
// ---------------------------------------------------------------------------
__global__ __launch_bounds__(256) void sake_main(
    const __hip_bfloat16* __restrict__ hb,
    const float* __restrict__ coord,
    const float* __restrict__ W1,   // f32 [129][128]; only row 0 used here
    const float* __restrict__ b1,
    const float* __restrict__ b2,
    const __hip_bfloat16* __restrict__ w1t,
    const __hip_bfloat16* __restrict__ w2t,
    float* __restrict__ part) {
  // A tile: 128 rows x 128 bf16 (256B/row), XOR-swizzled 16B units
  __shared__ __align__(16) char A1[NN * 256];
  __shared__ float d2s[NN];
  __shared__ float ssum[2][HID];

  const int tid = threadIdx.x;
  const int bid = blockIdx.x;
  const int b = bid >> 7;
  const int i = bid & 127;

  // pairwise squared distance, exact f32
  if (tid < NN) {
    const float* xj = coord + (size_t)(b * NN + tid) * 3;
    const float* xi = coord + (size_t)(b * NN + i) * 3;
    float dx = xj[0] - xi[0], dy = xj[1] - xi[1], dz = xj[2] - xi[2];
    d2s[tid] = dx * dx + dy * dy + dz * dz;
  }

  // stage A: row r = pair j=r: [0:64]=h[b,r], [64:128]=h[b,i]
  {
    const __hip_bfloat16* hbase = hb + (size_t)b * NN * F_IN;
    const __hip_bfloat16* hi_p = hb + (size_t)(b * NN + i) * F_IN;
#pragma unroll
    for (int it = 0; it < 8; ++it) {
      int u16 = it * 256 + tid;  // 16B-unit index, 2048 total
      int r = u16 >> 4;
      int u = u16 & 15;
      const __hip_bfloat16* src =
          (u < 8) ? (hbase + r * F_IN + u * 8) : (hi_p + (u - 8) * 8);
      int su = (u & 8) | ((u ^ r) & 7);  // swizzle 16B unit within row
      *reinterpret_cast<int4*>(A1 + r * 256 + su * 16) =
          *reinterpret_cast<const int4*>(src);
    }
  }
  __syncthreads();

  const int wave = tid >> 6;
  const int lane = tid & 63;
  const int lr = lane & 15;   // A-row / B-col / C-col within 16x16 tile
  const int kg = lane >> 4;   // k-group
  const int row_off = (wave >> 1) * 64;
  const int col_off = (wave & 1) * 64;

  f32x4 acc[4][4];

  // ---- layer 1 init: b1[col] + d2[row]*W1[0][col] (keeps d2 path exact f32)
#pragma unroll
  for (int ct = 0; ct < 4; ++ct) {
    int col = col_off + ct * 16 + lr;
    float w0 = W1[col];
    float bb = b1[col];
#pragma unroll
    for (int rt = 0; rt < 4; ++rt)
#pragma unroll
      for (int reg = 0; reg < 4; ++reg) {
        int row = row_off + rt * 16 + kg * 4 + reg;
        acc[rt][ct][reg] = bb + d2s[row] * w0;
      }
  }

  // ---- layer 1 MFMA K-loop (K=128, 4 steps of 32)
#pragma unroll
  for (int ks = 0; ks < 4; ++ks) {
    bf16x8 a[4], w[4];
    int kb = ks * 64 + kg * 16;  // byte offset within row
#pragma unroll
    for (int rt = 0; rt < 4; ++rt) {
      int r = row_off + rt * 16 + lr;
      a[rt] = *reinterpret_cast<const bf16x8*>(A1 + r * 256 + (kb ^ ((r & 7) << 4)));
    }
#pragma unroll
    for (int ct = 0; ct < 4; ++ct) {
      int c = col_off + ct * 16 + lr;
      w[ct] = *reinterpret_cast<const bf16x8*>(
          reinterpret_cast<const short*>(w1t) + c * HID + ks * 32 + kg * 8);
    }
#pragma unroll
    for (int rt = 0; rt < 4; ++rt)
#pragma unroll
      for (int ct = 0; ct < 4; ++ct)
        acc[rt][ct] = __builtin_amdgcn_mfma_f32_16x16x32_bf16(a[rt], w[ct],
                                                              acc[rt][ct], 0, 0, 0);
  }

  __syncthreads();  // all layer-1 A reads done before overwrite

  // ---- silu(z1) -> bf16 back into A1 (same swizzle)
#pragma unroll
  for (int rt = 0; rt < 4; ++rt)
#pragma unroll
    for (int ct = 0; ct < 4; ++ct)
#pragma unroll
      for (int reg = 0; reg < 4; ++reg) {
        float v = acc[rt][ct][reg];
        v = v / (1.f + __expf(-v));
        int row = row_off + rt * 16 + kg * 4 + reg;
        int col = col_off + ct * 16 + lr;
        int byo = (col * 2) ^ ((row & 7) << 4);
        *reinterpret_cast<__hip_bfloat16*>(A1 + row * 256 + byo) =
            __float2bfloat16(v);
      }
  __syncthreads();

  // ---- layer 2 init: b2
#pragma unroll
  for (int ct = 0; ct < 4; ++ct) {
    float bb = b2[col_off + ct * 16 + lr];
#pragma unroll
    for (int rt = 0; rt < 4; ++rt)
#pragma unroll
      for (int reg = 0; reg < 4; ++reg) acc[rt][ct][reg] = bb;
  }

  // ---- layer 2 MFMA K-loop
#pragma unroll
  for (int ks = 0; ks < 4; ++ks) {
    bf16x8 a[4], w[4];
    int kb = ks * 64 + kg * 16;
#pragma unroll
    for (int rt = 0; rt < 4; ++rt) {
      int r = row_off + rt * 16 + lr;
      a[rt] = *reinterpret_cast<const bf16x8*>(A1 + r * 256 + (kb ^ ((r & 7) << 4)));
    }
#pragma unroll
    for (int ct = 0; ct < 4; ++ct) {
      int c = col_off + ct * 16 + lr;
      w[ct] = *reinterpret_cast<const bf16x8*>(
          reinterpret_cast<const short*>(w2t) + c * HID + ks * 32 + kg * 8);
    }
#pragma unroll
    for (int rt = 0; rt < 4; ++rt)
#pragma unroll
      for (int ct = 0; ct < 4; ++ct)
        acc[rt][ct] = __builtin_amdgcn_mfma_f32_16x16x32_bf16(a[rt], w[ct],
                                                              acc[rt][ct], 0, 0, 0);
  }

  // ---- silu(z2) and column sums (sum over the 128 rows = pairs)
  float csum[4];
#pragma unroll
  for (int ct = 0; ct < 4; ++ct) {
    float s = 0.f;
#pragma unroll
    for (int rt = 0; rt < 4; ++rt)
#pragma unroll
      for (int reg = 0; reg < 4; ++reg) {
        float v = acc[rt][ct][reg];
        s += v / (1.f + __expf(-v));
      }
    csum[ct] = s;
  }
  // lanes {l, l+16, l+32, l+48} hold the same column -> reduce
#pragma unroll
  for (int ct = 0; ct < 4; ++ct) {
    float s = csum[ct];
    s += __shfl_down(s, 32);
    s += __shfl_down(s, 16);
    csum[ct] = s;
  }
  if (lane < 16) {
    int sel = wave >> 1;  // waves {0,1} -> 0, {2,3} -> 1 (disjoint cols per sel)
#pragma unroll
    for (int ct = 0; ct < 4; ++ct)
      ssum[sel][col_off + ct * 16 + lane] = csum[ct];
  }
  __syncthreads();
  if (tid < HID)
    part[(size_t)bid * HID + tid] = ssum[0][tid] + ssum[1][tid];
}

// ---------------------------------------------------------------------------
// Final: out[b] = (sum_i part[b,i]) @ W3 + 16384*b3   (all f32, exact)
// ---------------------------------------------------------------------------
__global__ void final_kernel(const float* __restrict__ part,
                             const float* __restrict__ W3,
                             const float* __restrict__ b3,
                             float* __restrict__ out) {
  __shared__ float s2[2][HID];
  __shared__ float s[HID];
  int b = blockIdx.x, t = threadIdx.x;
  int c = t & 127, half = t >> 7;
  float a = 0.f;
  for (int i = half * 64; i < half * 64 + 64; ++i)
    a += part[(size_t)(b * NN + i) * HID + c];
  s2[half][c] = a;
  __syncthreads();
  if (t < HID) s[t] = s2[0][t] + s2[1][t];
  __syncthreads();
  if (t < OUTF) {
    float o = 16384.f * b3[t];
    for (int c2 = 0; c2 < HID; ++c2) o += s[c2] * W3[c2 * OUTF + t];
    out[b * OUTF + t] = o;
  }
}

// ---------------------------------------------------------------------------
extern "C" void kernel_launch(void* const* d_in, const int* in_sizes, int n_in,
                              void* d_out, int out_size, void* d_ws, size_t ws_size,
                              hipStream_t stream) {
  const float* feat = (const float*)d_in[0];
  const float* coord = (const float*)d_in[1];
  const float* W1 = (const float*)d_in[2];
  const float* b1 = (const float*)d_in[3];
  const float* W2 = (const float*)d_in[4];
  const float* b2 = (const float*)d_in[5];
  const float* W3 = (const float*)d_in[6];
  const float* b3 = (const float*)d_in[7];
  float* out = (float*)d_out;

  // workspace layout (needs ~2.7 MB):
  char* ws = (char*)d_ws;
  __hip_bfloat16* hb = (__hip_bfloat16*)ws;                  // 512 KB
  __hip_bfloat16* w1t = (__hip_bfloat16*)(ws + 512 * 1024);  // 32 KB
  __hip_bfloat16* w2t = (__hip_bfloat16*)(ws + 544 * 1024);  // 32 KB
  float* part = (float*)(ws + 640 * 1024);                   // 2 MB

  prep_kernel<<<1024, 256, 0, stream>>>(feat, W1, W2, hb, w1t, w2t);
  sake_main<<<TOTAL, 256, 0, stream>>>(hb, coord, W1, b1, b2, w1t, w2t, part);
  final_kernel<<<NB, 256, 0, stream>>>(part, W3, b3, out);
}

// Round 2
// 72.871 us; speedup vs baseline: 1.7687x; 1.7687x over previous
//
#include <hip/hip_runtime.h>
#include <hip/hip_bf16.h>

// 32 graphs x 128 nodes, F=64, HID=128, OUT=64
#define F_IN 64
#define HID 128
#define OUTF 64
#define NN 128
#define NB 32
#define TOTAL 4096

typedef short bf16x8 __attribute__((ext_vector_type(8)));
typedef float f32x4 __attribute__((ext_vector_type(4)));

static __device__ __forceinline__ short f2bf(float v) {
  __hip_bfloat16 h = __float2bfloat16(v);
  return __builtin_bit_cast(short, h);
}

// silu via v_rcp_f32 (1-ulp) instead of IEEE divide (~8 insts -> ~5)
static __device__ __forceinline__ float fast_silu(float v) {
  return v * __builtin_amdgcn_rcpf(1.f + __expf(-v));
}

// ---------------------------------------------------------------------------
// prep0: feat -> bf16; Wcat^T bf16 [256][64] (c<128: W1[1+k][c], else W1[65+k][c-128]);
//        W2 -> bf16 transposed [col][k]
// ---------------------------------------------------------------------------
__global__ void prep0(const float* __restrict__ feat,
                      const float* __restrict__ W1,
                      const float* __restrict__ W2,
                      __hip_bfloat16* __restrict__ hb,
                      __hip_bfloat16* __restrict__ wcatT,
                      __hip_bfloat16* __restrict__ w2t) {
  int idx = blockIdx.x * 256 + threadIdx.x;
  if (idx < TOTAL * F_IN) hb[idx] = __float2bfloat16(feat[idx]);
  if (idx < 256 * F_IN) {
    int c = idx >> 6, k = idx & 63;
    float wv = (c < HID) ? W1[(1 + k) * HID + c] : W1[(65 + k) * HID + (c - HID)];
    wcatT[idx] = __float2bfloat16(wv);
  }
  if (idx < HID * HID) {
    int c = idx >> 7, k = idx & 127;
    w2t[c * HID + k] = __float2bfloat16(W2[k * HID + c]);
  }
}

// ---------------------------------------------------------------------------
// prep_uv: uv[n][c] = h[n] @ WcatT[c]  (c<128: u, c>=128: v + b1[c-128]), f32 out
// grid 256 blocks x 16 rows; 4 waves each own 64 cols; MFMA 16x16x32 bf16
// ---------------------------------------------------------------------------
__global__ __launch_bounds__(256) void prep_uv(
    const __hip_bfloat16* __restrict__ hb,
    const __hip_bfloat16* __restrict__ wcatT,
    const float* __restrict__ b1,
    float* __restrict__ uv) {
  const int wave = threadIdx.x >> 6, lane = threadIdx.x & 63;
  const int lr = lane & 15, kg = lane >> 4;
  const int r0 = blockIdx.x * 16;
  f32x4 acc[4];
#pragma unroll
  for (int ct = 0; ct < 4; ++ct) acc[ct] = {0.f, 0.f, 0.f, 0.f};
#pragma unroll
  for (int ks = 0; ks < 2; ++ks) {
    bf16x8 a = *reinterpret_cast<const bf16x8*>(hb + (r0 + lr) * F_IN + ks * 32 + kg * 8);
#pragma unroll
    for (int ct = 0; ct < 4; ++ct) {
      const int c = wave * 64 + ct * 16 + lr;
      bf16x8 w = *reinterpret_cast<const bf16x8*>(
          reinterpret_cast<const short*>(wcatT) + c * F_IN + ks * 32 + kg * 8);
      acc[ct] = __builtin_amdgcn_mfma_f32_16x16x32_bf16(a, w, acc[ct], 0, 0, 0);
    }
  }
#pragma unroll
  for (int ct = 0; ct < 4; ++ct) {
    const int c = wave * 64 + ct * 16 + lr;
    const float badd = (c >= HID) ? b1[c - HID] : 0.f;
#pragma unroll
    for (int reg = 0; reg < 4; ++reg) {
      const int r = r0 + kg * 4 + reg;
      uv[(size_t)r * 256 + c] = acc[ct][reg] + badd;
    }
  }
}

// ---------------------------------------------------------------------------
// main: one block per (b,i). z1 assembled elementwise from u/v/d2 (NO layer-1
// GEMM), silu'd, packed bf16x8 into swizzled LDS; layer-2 MFMA; silu2+colsum.
// ---------------------------------------------------------------------------
__global__ __launch_bounds__(256) void sake_main(
    const float* __restrict__ coord,
    const float* __restrict__ W1,   // only row 0 (d2 weights) used
    const float* __restrict__ b2,
    const float* __restrict__ uv,
    const __hip_bfloat16* __restrict__ w2t,
    float* __restrict__ part) {
  __shared__ __align__(16) char A1[NN * 256];
  __shared__ float d2s[NN];
  __shared__ float ssum[2][HID];

  const int tid = threadIdx.x;
  const int bid = blockIdx.x;
  const int b = bid >> 7;
  const int i = bid & 127;

  if (tid < NN) {
    const float* xj = coord + (size_t)(b * NN + tid) * 3;
    const float* xi = coord + (size_t)(b * NN + i) * 3;
    float dx = xj[0] - xi[0], dy = xj[1] - xi[1], dz = xj[2] - xi[2];
    d2s[tid] = dx * dx + dy * dy + dz * dz;
  }
  __syncthreads();

  // ---- assemble z1 rows: thread owns 8 cols (cg) x 8 rows (rg) ----
  {
    const int cg = tid & 15;
    const int rg = tid >> 4;
    const int c0 = cg * 8;
    const f32x4 w0a = *reinterpret_cast<const f32x4*>(W1 + c0);
    const f32x4 w0b = *reinterpret_cast<const f32x4*>(W1 + c0 + 4);
    const float* vbp = uv + (size_t)(b * NN + i) * 256 + HID + c0;
    const f32x4 vba = *reinterpret_cast<const f32x4*>(vbp);
    const f32x4 vbb = *reinterpret_cast<const f32x4*>(vbp + 4);
#pragma unroll
    for (int it = 0; it < 8; ++it) {
      const int r = rg * 8 + it;
      const float* up = uv + (size_t)(b * NN + r) * 256 + c0;
      const f32x4 ua = *reinterpret_cast<const f32x4*>(up);
      const f32x4 ub = *reinterpret_cast<const f32x4*>(up + 4);
      const float d2r = d2s[r];
      bf16x8 pk;
#pragma unroll
      for (int j = 0; j < 4; ++j)
        pk[j] = f2bf(fast_silu(fmaf(d2r, w0a[j], vba[j] + ua[j])));
#pragma unroll
      for (int j = 0; j < 4; ++j)
        pk[4 + j] = f2bf(fast_silu(fmaf(d2r, w0b[j], vbb[j] + ub[j])));
      const int byo = (cg * 16) ^ (it << 4);  // r&7 == it
      *reinterpret_cast<bf16x8*>(A1 + r * 256 + byo) = pk;
    }
  }
  __syncthreads();

  const int wave = tid >> 6;
  const int lane = tid & 63;
  const int lr = lane & 15;
  const int kg = lane >> 4;
  const int row_off = (wave >> 1) * 64;
  const int col_off = (wave & 1) * 64;

  f32x4 acc[4][4];
#pragma unroll
  for (int ct = 0; ct < 4; ++ct) {
    const float bb = b2[col_off + ct * 16 + lr];
#pragma unroll
    for (int rt = 0; rt < 4; ++rt)
#pragma unroll
      for (int reg = 0; reg < 4; ++reg) acc[rt][ct][reg] = bb;
  }

#pragma unroll
  for (int ks = 0; ks < 4; ++ks) {
    bf16x8 a[4], w[4];
    const int kb = ks * 64 + kg * 16;
#pragma unroll
    for (int rt = 0; rt < 4; ++rt) {
      const int r = row_off + rt * 16 + lr;
      a[rt] = *reinterpret_cast<const bf16x8*>(A1 + r * 256 + (kb ^ ((r & 7) << 4)));
    }
#pragma unroll
    for (int ct = 0; ct < 4; ++ct) {
      const int c = col_off + ct * 16 + lr;
      w[ct] = *reinterpret_cast<const bf16x8*>(
          reinterpret_cast<const short*>(w2t) + c * HID + ks * 32 + kg * 8);
    }
#pragma unroll
    for (int rt = 0; rt < 4; ++rt)
#pragma unroll
      for (int ct = 0; ct < 4; ++ct)
        acc[rt][ct] = __builtin_amdgcn_mfma_f32_16x16x32_bf16(a[rt], w[ct],
                                                              acc[rt][ct], 0, 0, 0);
  }

  // ---- silu(z2) and column sums over the 128 rows ----
  float csum[4];
#pragma unroll
  for (int ct = 0; ct < 4; ++ct) {
    float s = 0.f;
#pragma unroll
    for (int rt = 0; rt < 4; ++rt)
#pragma unroll
      for (int reg = 0; reg < 4; ++reg) s += fast_silu(acc[rt][ct][reg]);
    csum[ct] = s;
  }
#pragma unroll
  for (int ct = 0; ct < 4; ++ct) {
    float s = csum[ct];
    s += __shfl_down(s, 32);
    s += __shfl_down(s, 16);
    csum[ct] = s;
  }
  if (lane < 16) {
    const int sel = wave >> 1;  // waves {0,1}->0, {2,3}->1 (disjoint cols per sel)
#pragma unroll
    for (int ct = 0; ct < 4; ++ct)
      ssum[sel][col_off + ct * 16 + lane] = csum[ct];
  }
  __syncthreads();
  if (tid < HID)
    part[(size_t)bid * HID + tid] = ssum[0][tid] + ssum[1][tid];
}

// ---------------------------------------------------------------------------
// final: out[b] = (sum_i part[b,i]) @ W3 + 16384*b3   (all f32, exact)
// ---------------------------------------------------------------------------
__global__ void final_kernel(const float* __restrict__ part,
                             const float* __restrict__ W3,
                             const float* __restrict__ b3,
                             float* __restrict__ out) {
  __shared__ float s2[2][HID];
  __shared__ float s[HID];
  int b = blockIdx.x, t = threadIdx.x;
  int c = t & 127, half = t >> 7;
  float a = 0.f;
  for (int i = half * 64; i < half * 64 + 64; ++i)
    a += part[(size_t)(b * NN + i) * HID + c];
  s2[half][c] = a;
  __syncthreads();
  if (t < HID) s[t] = s2[0][t] + s2[1][t];
  __syncthreads();
  if (t < OUTF) {
    float o = 16384.f * b3[t];
    for (int c2 = 0; c2 < HID; ++c2) o += s[c2] * W3[c2 * OUTF + t];
    out[b * OUTF + t] = o;
  }
}

// ---------------------------------------------------------------------------
extern "C" void kernel_launch(void* const* d_in, const int* in_sizes, int n_in,
                              void* d_out, int out_size, void* d_ws, size_t ws_size,
                              hipStream_t stream) {
  const float* feat = (const float*)d_in[0];
  const float* coord = (const float*)d_in[1];
  const float* W1 = (const float*)d_in[2];
  const float* b1 = (const float*)d_in[3];
  const float* W2 = (const float*)d_in[4];
  const float* b2 = (const float*)d_in[5];
  const float* W3 = (const float*)d_in[6];
  const float* b3 = (const float*)d_in[7];
  float* out = (float*)d_out;

  // workspace layout (~6.6 MB)
  char* ws = (char*)d_ws;
  __hip_bfloat16* hb = (__hip_bfloat16*)ws;                      // 512 KB
  __hip_bfloat16* wcatT = (__hip_bfloat16*)(ws + 512 * 1024);    // 32 KB
  __hip_bfloat16* w2t = (__hip_bfloat16*)(ws + 544 * 1024);      // 32 KB
  float* uv = (float*)(ws + 576 * 1024);                         // 4 MB
  float* part = (float*)(ws + 576 * 1024 + 4096 * 1024);         // 2 MB

  prep0<<<1024, 256, 0, stream>>>(feat, W1, W2, hb, wcatT, w2t);
  prep_uv<<<256, 256, 0, stream>>>(hb, wcatT, b1, uv);
  sake_main<<<TOTAL, 256, 0, stream>>>(coord, W1, b2, uv, w2t, part);
  final_kernel<<<NB, 256, 0, stream>>>(part, W3, b3, out);
}

// Round 3
// 70.536 us; speedup vs baseline: 1.8273x; 1.0331x over previous
//
#include <hip/hip_runtime.h>
#include <hip/hip_bf16.h>

// 32 graphs x 128 nodes, F=64, HID=128, OUT=64
#define F_IN 64
#define HID 128
#define OUTF 64
#define NN 128
#define NB 32
#define TOTAL 4096

typedef short bf16x8 __attribute__((ext_vector_type(8)));
typedef float f32x4 __attribute__((ext_vector_type(4)));

static __device__ __forceinline__ short f2bf(float v) {
  __hip_bfloat16 h = __float2bfloat16(v);
  return __builtin_bit_cast(short, h);
}
// silu via v_rcp_f32 (1-ulp) instead of IEEE divide
static __device__ __forceinline__ float fast_silu(float v) {
  return v * __builtin_amdgcn_rcpf(1.f + __expf(-v));
}

// ---------------------------------------------------------------------------
// uv_prep: 256 blocks x 256 thr. Block handles 16 nodes (rows).
//   uv[n][c] = h[n] @ Wcat[:,c]  (c<128: u = h@W1[1:65];  c>=128: v = h@W1[65:129] + b1)
// wcat staged in LDS bf16 (built from W1, coalesced over cols), XOR-swizzled.
// Blocks 0-63 additionally build the swizzled bf16 W2^T (w2swz) in global.
// ---------------------------------------------------------------------------
__global__ __launch_bounds__(256) void uv_prep(
    const float* __restrict__ feat,
    const float* __restrict__ W1,
    const float* __restrict__ W2,
    const float* __restrict__ b1,
    float* __restrict__ uv,
    __hip_bfloat16* __restrict__ w2swz) {
  __shared__ __align__(16) char wcat[256 * 128];  // 256 cols x 64 k (bf16), 128B rows
  const int tid = threadIdx.x;

  // build wcat: thread owns col c = tid; reads coalesced across threads
  {
    const int c = tid;
    const int cc = c & 127;
    const int rbase = (c < HID) ? 1 : 65;
#pragma unroll
    for (int p = 0; p < 8; ++p) {
      bf16x8 pk;
#pragma unroll
      for (int m = 0; m < 8; ++m)
        pk[m] = f2bf(W1[(rbase + p * 8 + m) * HID + cc]);
      *reinterpret_cast<bf16x8*>(wcat + c * 128 + ((p ^ (c & 7)) << 4)) = pk;
    }
  }
  // blocks 0-63: emit swizzled W2^T bf16 [c][k] (256B rows, 16B-slot XOR swizzle)
  if (blockIdx.x < 64) {
    const int e = blockIdx.x * 256 + tid;  // 0..16383
    const int kk = e >> 7, cc2 = e & 127;
    const int byo = cc2 * 256 + (((kk >> 3) ^ (cc2 & 7)) << 4) + (kk & 7) * 2;
    *reinterpret_cast<__hip_bfloat16*>(reinterpret_cast<char*>(w2swz) + byo) =
        __float2bfloat16(W2[kk * HID + cc2]);
  }
  __syncthreads();

  const int wave = tid >> 6, lane = tid & 63;
  const int lr = lane & 15, kg = lane >> 4;
  const int r0 = blockIdx.x * 16;

  f32x4 acc[4];
#pragma unroll
  for (int ct = 0; ct < 4; ++ct) acc[ct] = {0.f, 0.f, 0.f, 0.f};

#pragma unroll
  for (int ks = 0; ks < 2; ++ks) {
    const float* fp = feat + (size_t)(r0 + lr) * F_IN + ks * 32 + kg * 8;
    const f32x4 fa = *reinterpret_cast<const f32x4*>(fp);
    const f32x4 fb = *reinterpret_cast<const f32x4*>(fp + 4);
    bf16x8 a;
#pragma unroll
    for (int m = 0; m < 4; ++m) {
      a[m] = f2bf(fa[m]);
      a[4 + m] = f2bf(fb[m]);
    }
    const int slot = ks * 4 + kg;
#pragma unroll
    for (int ct = 0; ct < 4; ++ct) {
      const int c = wave * 64 + ct * 16 + lr;
      const bf16x8 w = *reinterpret_cast<const bf16x8*>(
          wcat + c * 128 + ((slot ^ (c & 7)) << 4));
      acc[ct] = __builtin_amdgcn_mfma_f32_16x16x32_bf16(a, w, acc[ct], 0, 0, 0);
    }
  }
#pragma unroll
  for (int ct = 0; ct < 4; ++ct) {
    const int c = wave * 64 + ct * 16 + lr;
    const float badd = (c >= HID) ? b1[c - HID] : 0.f;
#pragma unroll
    for (int reg = 0; reg < 4; ++reg) {
      const int r = r0 + kg * 4 + reg;
      uv[(size_t)r * 256 + c] = acc[ct][reg] + badd;
    }
  }
}

// ---------------------------------------------------------------------------
// main: 4096 blocks (b,i) x 512 thr (8 waves). Wave owns 16 pair-rows x 128 cols.
// z1 built straight into A-fragments (f32 math, exact d2), layer-2 MFMA from
// LDS-staged swizzled W2, silu2 + colsum -> part[bid][128]. Two barriers total.
// ---------------------------------------------------------------------------
__global__ __launch_bounds__(512) void sake_main(
    const float* __restrict__ coord,
    const float* __restrict__ W1,   // row 0 = d2 weights
    const float* __restrict__ b2,
    const float* __restrict__ uv,
    const __hip_bfloat16* __restrict__ w2swz,
    float* __restrict__ part) {
  __shared__ __align__(16) char w2lds[HID * 256];  // 32 KB, already swizzled
  __shared__ float ssum[8][HID];

  const int tid = threadIdx.x;
  // XCD-aware swizzle: 4096 blocks -> 512 contiguous per XCD (graphs stay local)
  const int bid = (blockIdx.x & 7) * 512 + (blockIdx.x >> 3);
  const int b = bid >> 7;
  const int i = bid & 127;

  // stage w2swz -> LDS (linear copy; data pre-swizzled)
#pragma unroll
  for (int p = 0; p < 4; ++p) {
    const int o = (tid + p * 512) * 16;
    *reinterpret_cast<int4*>(w2lds + o) =
        *reinterpret_cast<const int4*>(reinterpret_cast<const char*>(w2swz) + o);
  }

  const int wave = tid >> 6, lane = tid & 63;
  const int lr = lane & 15, kg = lane >> 4;
  const int j = wave * 16 + lr;  // this thread's pair row (A-row)

  // d2 for row j (exact f32, per-thread, no LDS)
  const float* xj = coord + (size_t)(b * NN + j) * 3;
  const float* xi = coord + (size_t)(b * NN + i) * 3;
  const float dx = xj[0] - xi[0], dy = xj[1] - xi[1], dz = xj[2] - xi[2];
  const float d2j = dx * dx + dy * dy + dz * dz;

  // acc init = b2[col]
  f32x4 acc[8];
#pragma unroll
  for (int ct = 0; ct < 8; ++ct) {
    const float bb = b2[ct * 16 + lr];
    acc[ct] = {bb, bb, bb, bb};
  }

  const float* urow = uv + (size_t)(b * NN + j) * 256;
  const float* vrow = uv + (size_t)(b * NN + i) * 256 + HID;

  __syncthreads();  // w2lds ready

#pragma unroll
  for (int ks = 0; ks < 4; ++ks) {
    const int c0 = ks * 32 + kg * 8;
    const f32x4 ua = *reinterpret_cast<const f32x4*>(urow + c0);
    const f32x4 ub = *reinterpret_cast<const f32x4*>(urow + c0 + 4);
    const f32x4 va = *reinterpret_cast<const f32x4*>(vrow + c0);
    const f32x4 vb = *reinterpret_cast<const f32x4*>(vrow + c0 + 4);
    const f32x4 wa = *reinterpret_cast<const f32x4*>(W1 + c0);
    const f32x4 wb = *reinterpret_cast<const f32x4*>(W1 + c0 + 4);
    bf16x8 a;
#pragma unroll
    for (int m = 0; m < 4; ++m) {
      a[m] = f2bf(fast_silu(fmaf(d2j, wa[m], ua[m] + va[m])));
      a[4 + m] = f2bf(fast_silu(fmaf(d2j, wb[m], ub[m] + vb[m])));
    }
    const int slot = ks * 4 + kg;
    const int rbase = lr * 256 + ((slot ^ (lr & 7)) << 4);
#pragma unroll
    for (int ct = 0; ct < 8; ++ct) {
      const bf16x8 w = *reinterpret_cast<const bf16x8*>(w2lds + rbase + ct * 4096);
      acc[ct] = __builtin_amdgcn_mfma_f32_16x16x32_bf16(a, w, acc[ct], 0, 0, 0);
    }
  }

  // silu(z2) + column sums (over this wave's 16 rows), then cross-wave reduce
  float csum[8];
#pragma unroll
  for (int ct = 0; ct < 8; ++ct) {
    float s = fast_silu(acc[ct][0]) + fast_silu(acc[ct][1]) +
              fast_silu(acc[ct][2]) + fast_silu(acc[ct][3]);
    s += __shfl_xor(s, 16);
    s += __shfl_xor(s, 32);
    csum[ct] = s;
  }
  if (lane < 16) {
#pragma unroll
    for (int ct = 0; ct < 8; ++ct) ssum[wave][ct * 16 + lane] = csum[ct];
  }
  __syncthreads();
  if (tid < HID) {
    float s = 0.f;
#pragma unroll
    for (int w = 0; w < 8; ++w) s += ssum[w][tid];
    part[(size_t)bid * HID + tid] = s;
  }
}

// ---------------------------------------------------------------------------
// final: out[b] = (sum_i part[b,i]) @ W3 + 16384*b3   (all f32, exact)
// ---------------------------------------------------------------------------
__global__ void final_kernel(const float* __restrict__ part,
                             const float* __restrict__ W3,
                             const float* __restrict__ b3,
                             float* __restrict__ out) {
  __shared__ float s2[2][HID];
  __shared__ float s[HID];
  int b = blockIdx.x, t = threadIdx.x;
  int c = t & 127, half = t >> 7;
  float a = 0.f;
  for (int i = half * 64; i < half * 64 + 64; ++i)
    a += part[(size_t)(b * NN + i) * HID + c];
  s2[half][c] = a;
  __syncthreads();
  if (t < HID) s[t] = s2[0][t] + s2[1][t];
  __syncthreads();
  if (t < OUTF) {
    float o = 16384.f * b3[t];
    for (int c2 = 0; c2 < HID; ++c2) o += s[c2] * W3[c2 * OUTF + t];
    out[b * OUTF + t] = o;
  }
}

// ---------------------------------------------------------------------------
extern "C" void kernel_launch(void* const* d_in, const int* in_sizes, int n_in,
                              void* d_out, int out_size, void* d_ws, size_t ws_size,
                              hipStream_t stream) {
  const float* feat = (const float*)d_in[0];
  const float* coord = (const float*)d_in[1];
  const float* W1 = (const float*)d_in[2];
  const float* b1 = (const float*)d_in[3];
  const float* W2 = (const float*)d_in[4];
  const float* b2 = (const float*)d_in[5];
  const float* W3 = (const float*)d_in[6];
  const float* b3 = (const float*)d_in[7];
  float* out = (float*)d_out;

  // workspace layout (~6.1 MB)
  char* ws = (char*)d_ws;
  __hip_bfloat16* w2swz = (__hip_bfloat16*)ws;         // 32 KB (swizzled W2^T bf16)
  float* uv = (float*)(ws + 64 * 1024);                // 4 MB
  float* part = (float*)(ws + 64 * 1024 + 4096 * 1024);  // 2 MB

  uv_prep<<<256, 256, 0, stream>>>(feat, W1, W2, b1, uv, w2swz);
  sake_main<<<TOTAL, 512, 0, stream>>>(coord, W1, b2, uv, w2swz, part);
  final_kernel<<<NB, 256, 0, stream>>>(part, W3, b3, out);
}

// Round 4
// 68.824 us; speedup vs baseline: 1.8727x; 1.0249x over previous
//
#include <hip/hip_runtime.h>
#include <hip/hip_bf16.h>

// 32 graphs x 128 nodes, F=64, HID=128, OUT=64
#define F_IN 64
#define HID 128
#define OUTF 64
#define NN 128
#define NB 32
#define TOTAL 4096

typedef short bf16x8 __attribute__((ext_vector_type(8)));
typedef float f32x4 __attribute__((ext_vector_type(4)));

static __device__ __forceinline__ short f2bf(float v) {
  __hip_bfloat16 h = __float2bfloat16(v);
  return __builtin_bit_cast(short, h);
}
// silu via v_rcp_f32 (1-ulp) instead of IEEE divide
static __device__ __forceinline__ float fast_silu(float v) {
  return v * __builtin_amdgcn_rcpf(1.f + __expf(-v));
}

// ---------------------------------------------------------------------------
// uv_prep: 256 blocks x 256 thr. Block handles 16 nodes (rows).
//   uv[n][c] = h[n] @ Wcat[:,c]  (c<128: u = h@W1[1:65];  c>=128: v = h@W1[65:129] + b1)
// Blocks 0-63 additionally emit swizzled bf16 W2^T (w2swz) to global.
// ---------------------------------------------------------------------------
__global__ __launch_bounds__(256) void uv_prep(
    const float* __restrict__ feat,
    const float* __restrict__ W1,
    const float* __restrict__ W2,
    const float* __restrict__ b1,
    float* __restrict__ uv,
    __hip_bfloat16* __restrict__ w2swz) {
  __shared__ __align__(16) char wcat[256 * 128];  // 256 cols x 64 k (bf16)
  const int tid = threadIdx.x;

  {
    const int c = tid;
    const int cc = c & 127;
    const int rbase = (c < HID) ? 1 : 65;
#pragma unroll
    for (int p = 0; p < 8; ++p) {
      bf16x8 pk;
#pragma unroll
      for (int m = 0; m < 8; ++m)
        pk[m] = f2bf(W1[(rbase + p * 8 + m) * HID + cc]);
      *reinterpret_cast<bf16x8*>(wcat + c * 128 + ((p ^ (c & 7)) << 4)) = pk;
    }
  }
  if (blockIdx.x < 64) {
    const int e = blockIdx.x * 256 + tid;  // 0..16383
    const int kk = e >> 7, cc2 = e & 127;
    const int byo = cc2 * 256 + (((kk >> 3) ^ (cc2 & 7)) << 4) + (kk & 7) * 2;
    *reinterpret_cast<__hip_bfloat16*>(reinterpret_cast<char*>(w2swz) + byo) =
        __float2bfloat16(W2[kk * HID + cc2]);
  }
  __syncthreads();

  const int wave = tid >> 6, lane = tid & 63;
  const int lr = lane & 15, kg = lane >> 4;
  const int r0 = blockIdx.x * 16;

  f32x4 acc[4];
#pragma unroll
  for (int ct = 0; ct < 4; ++ct) acc[ct] = {0.f, 0.f, 0.f, 0.f};

#pragma unroll
  for (int ks = 0; ks < 2; ++ks) {
    const float* fp = feat + (size_t)(r0 + lr) * F_IN + ks * 32 + kg * 8;
    const f32x4 fa = *reinterpret_cast<const f32x4*>(fp);
    const f32x4 fb = *reinterpret_cast<const f32x4*>(fp + 4);
    bf16x8 a;
#pragma unroll
    for (int m = 0; m < 4; ++m) {
      a[m] = f2bf(fa[m]);
      a[4 + m] = f2bf(fb[m]);
    }
    const int slot = ks * 4 + kg;
#pragma unroll
    for (int ct = 0; ct < 4; ++ct) {
      const int c = wave * 64 + ct * 16 + lr;
      const bf16x8 w = *reinterpret_cast<const bf16x8*>(
          wcat + c * 128 + ((slot ^ (c & 7)) << 4));
      acc[ct] = __builtin_amdgcn_mfma_f32_16x16x32_bf16(a, w, acc[ct], 0, 0, 0);
    }
  }
#pragma unroll
  for (int ct = 0; ct < 4; ++ct) {
    const int c = wave * 64 + ct * 16 + lr;
    const float badd = (c >= HID) ? b1[c - HID] : 0.f;
#pragma unroll
    for (int reg = 0; reg < 4; ++reg) {
      const int r = r0 + kg * 4 + reg;
      uv[(size_t)r * 256 + c] = acc[ct][reg] + badd;
    }
  }
}

// ---------------------------------------------------------------------------
// main: 1024 blocks = (graph b, group of 4 i) x 512 thr (8 waves).
// Wave = (i = ig*4 + wave>>1, j-half = wave&1): 64 rows x 128 cols.
// B-frags (W2) loaded once per ks into 32 VGPRs, reused by 4 A-tiles ->
// 4x less LDS traffic than round 3. z1 built in-register (f32, exact d2).
// ---------------------------------------------------------------------------
__global__ __launch_bounds__(512, 2) void sake_main(
    const float* __restrict__ coord,
    const float* __restrict__ W1,   // row 0 = d2 weights
    const float* __restrict__ b2,
    const float* __restrict__ uv,
    const __hip_bfloat16* __restrict__ w2swz,
    float* __restrict__ part) {
  __shared__ __align__(16) char w2lds[HID * 256];  // 32 KB, pre-swizzled
  __shared__ float ssum[8][HID];

  const int tid = threadIdx.x;
  // XCD swizzle: 1024 = 8 XCD x 128; 4 graphs per XCD (uv stays L2-local)
  const int bid = (blockIdx.x & 7) * 128 + (blockIdx.x >> 3);
  const int b = bid >> 5;
  const int ig = bid & 31;

  // stage pre-swizzled W2 -> LDS (linear copy)
#pragma unroll
  for (int p = 0; p < 4; ++p) {
    const int o = (tid + p * 512) * 16;
    *reinterpret_cast<int4*>(w2lds + o) =
        *reinterpret_cast<const int4*>(reinterpret_cast<const char*>(w2swz) + o);
  }

  const int wave = tid >> 6, lane = tid & 63;
  const int lr = lane & 15, kg = lane >> 4;
  const int i = ig * 4 + (wave >> 1);
  const int j0 = (wave & 1) * 64;

  // d2 for this thread's 4 rows (exact f32)
  const float* xi = coord + (size_t)(b * NN + i) * 3;
  const float xix = xi[0], xiy = xi[1], xiz = xi[2];
  float d2t[4];
#pragma unroll
  for (int t = 0; t < 4; ++t) {
    const float* xj = coord + (size_t)(b * NN + j0 + t * 16 + lr) * 3;
    const float dx = xj[0] - xix, dy = xj[1] - xiy, dz = xj[2] - xiz;
    d2t[t] = dx * dx + dy * dy + dz * dz;
  }

  // acc init = b2[col]
  f32x4 acc[4][8];
#pragma unroll
  for (int ct = 0; ct < 8; ++ct) {
    const float bb = b2[ct * 16 + lr];
#pragma unroll
    for (int t = 0; t < 4; ++t) acc[t][ct] = {bb, bb, bb, bb};
  }

  const float* vrow = uv + ((size_t)b * NN + i) * 256 + HID;
  const float* urow0 = uv + ((size_t)b * NN + j0 + lr) * 256;

  __syncthreads();  // w2lds ready

#pragma unroll
  for (int ks = 0; ks < 4; ++ks) {
    const int c0 = ks * 32 + kg * 8;
    // B-fragments for this ks: 8 frags held in regs, reused by 4 A-tiles
    bf16x8 wf[8];
    const int rbase = lr * 256 + ((((ks << 2) | kg) ^ (lr & 7)) << 4);
#pragma unroll
    for (int ct = 0; ct < 8; ++ct)
      wf[ct] = *reinterpret_cast<const bf16x8*>(w2lds + rbase + ct * 4096);

    const f32x4 va = *reinterpret_cast<const f32x4*>(vrow + c0);
    const f32x4 vb = *reinterpret_cast<const f32x4*>(vrow + c0 + 4);
    const f32x4 wa = *reinterpret_cast<const f32x4*>(W1 + c0);
    const f32x4 wb = *reinterpret_cast<const f32x4*>(W1 + c0 + 4);

#pragma unroll
    for (int t = 0; t < 4; ++t) {
      const float* up = urow0 + t * 4096 + c0;  // row j0+t*16+lr
      const f32x4 ua = *reinterpret_cast<const f32x4*>(up);
      const f32x4 ub = *reinterpret_cast<const f32x4*>(up + 4);
      bf16x8 a;
#pragma unroll
      for (int m = 0; m < 4; ++m) {
        a[m] = f2bf(fast_silu(fmaf(d2t[t], wa[m], ua[m] + va[m])));
        a[4 + m] = f2bf(fast_silu(fmaf(d2t[t], wb[m], ub[m] + vb[m])));
      }
#pragma unroll
      for (int ct = 0; ct < 8; ++ct)
        acc[t][ct] = __builtin_amdgcn_mfma_f32_16x16x32_bf16(a, wf[ct],
                                                             acc[t][ct], 0, 0, 0);
    }
  }

  // silu(z2) + column sums over this wave's 64 rows
  float csum[8];
#pragma unroll
  for (int ct = 0; ct < 8; ++ct) {
    float s = 0.f;
#pragma unroll
    for (int t = 0; t < 4; ++t)
#pragma unroll
      for (int reg = 0; reg < 4; ++reg) {
        const float v = acc[t][ct][reg];
        s = fmaf(v, __builtin_amdgcn_rcpf(1.f + __expf(-v)), s);
      }
    s += __shfl_xor(s, 16);
    s += __shfl_xor(s, 32);
    csum[ct] = s;
  }
  if (lane < 16) {
#pragma unroll
    for (int ct = 0; ct < 8; ++ct) ssum[wave][ct * 16 + lane] = csum[ct];
  }
  __syncthreads();
  if (tid < HID) {
    float s = 0.f;
#pragma unroll
    for (int w = 0; w < 8; ++w) s += ssum[w][tid];
    part[(size_t)bid * HID + tid] = s;  // per-block partial (4 i x 128 j summed)
  }
}

// ---------------------------------------------------------------------------
// final: out[b] = (sum_{g<32} part[b*32+g]) @ W3 + 16384*b3   (all f32, exact)
// ---------------------------------------------------------------------------
__global__ void final_kernel(const float* __restrict__ part,
                             const float* __restrict__ W3,
                             const float* __restrict__ b3,
                             float* __restrict__ out) {
  __shared__ float s2[2][HID];
  __shared__ float s[HID];
  int b = blockIdx.x, t = threadIdx.x;
  int c = t & 127, half = t >> 7;
  float a = 0.f;
  for (int g = half * 16; g < half * 16 + 16; ++g)
    a += part[(size_t)(b * 32 + g) * HID + c];
  s2[half][c] = a;
  __syncthreads();
  if (t < HID) s[t] = s2[0][t] + s2[1][t];
  __syncthreads();
  if (t < OUTF) {
    float o = 16384.f * b3[t];
    for (int c2 = 0; c2 < HID; ++c2) o += s[c2] * W3[c2 * OUTF + t];
    out[b * OUTF + t] = o;
  }
}

// ---------------------------------------------------------------------------
extern "C" void kernel_launch(void* const* d_in, const int* in_sizes, int n_in,
                              void* d_out, int out_size, void* d_ws, size_t ws_size,
                              hipStream_t stream) {
  const float* feat = (const float*)d_in[0];
  const float* coord = (const float*)d_in[1];
  const float* W1 = (const float*)d_in[2];
  const float* b1 = (const float*)d_in[3];
  const float* W2 = (const float*)d_in[4];
  const float* b2 = (const float*)d_in[5];
  const float* W3 = (const float*)d_in[6];
  const float* b3 = (const float*)d_in[7];
  float* out = (float*)d_out;

  // workspace layout (~4.6 MB)
  char* ws = (char*)d_ws;
  __hip_bfloat16* w2swz = (__hip_bfloat16*)ws;            // 32 KB (swizzled W2^T)
  float* uv = (float*)(ws + 64 * 1024);                   // 4 MB
  float* part = (float*)(ws + 64 * 1024 + 4096 * 1024);   // 512 KB (1024 x 128)

  uv_prep<<<256, 256, 0, stream>>>(feat, W1, W2, b1, uv, w2swz);
  sake_main<<<1024, 512, 0, stream>>>(coord, W1, b2, uv, w2swz, part);
  final_kernel<<<NB, 256, 0, stream>>>(part, W3, b3, out);
}